// Round 6
// baseline (82.047 us; speedup 1.0000x reference)
//
#include <hip/hip_runtime.h>

// LinearAttention fp32 [4,16,4096,64]: out = (Q' (K'^T V)) / (Q'.k_sum + eps), X' = elu(X)+1.
// Pass 1 (kv_mfma): per (bh, 128-row chunk), TWO 64-row subtiles staged as bf16
//   transposed in 17KB LDS (conflict-free XOR swizzle), mfma_f32_16x16x32_bf16
//   accumulating across subtiles; ksum fp32 via wave shfl-reduce. High occupancy
//   (small LDS + launch_bounds) is the point: pass is latency-bound otherwise.
// Pass 1b (reduce_partials): fold NPB partials per bh.
// Pass 2 (out_kernel): unchanged (measured ~HBM roofline).

#define EPS_LA 1e-6f

constexpr int BH = 64;
constexpr int SEQ = 4096;
constexpr int DIM = 64;
constexpr int KVELEM = DIM * DIM + DIM;  // 4160
constexpr int NPB = 32;                  // partial blocks per bh
constexpr int SUBT = 2;                  // 64-row subtiles per block
constexpr int SCH = SEQ / NPB;           // 128 s-rows per block

typedef short bf16x8 __attribute__((ext_vector_type(8)));
typedef float f32x4 __attribute__((ext_vector_type(4)));

__device__ __forceinline__ float elu1(float x) {
    return x > 0.f ? x + 1.f : __expf(x);
}
__device__ __forceinline__ void elu4(float4& v) {
    v.x = elu1(v.x); v.y = elu1(v.y); v.z = elu1(v.z); v.w = elu1(v.w);
}

// fp32 -> bf16 (RNE; inputs finite)
__device__ __forceinline__ unsigned int f2bf(float x) {
    unsigned int u = __float_as_uint(x);
    return (u + 0x7fffu + ((u >> 16) & 1u)) >> 16;
}
__device__ __forceinline__ unsigned int pack2bf(float lo, float hi) {
    return f2bf(lo) | (f2bf(hi) << 16);
}

// Dword index into KT/VT[64 d-rows][32 s-pairs].
// XOR pattern ((d>>1)^(d>>2))&7 gives: staging b32 writes 2 lanes/bank (free),
// MFMA b128 reads 8 lanes/bank-group (b128 minimum). Keeps 16B alignment.
__device__ __forceinline__ int swz(int d, int s2) {
    return d * 32 + (s2 ^ ((((d >> 1) ^ (d >> 2)) & 7) << 2));
}

template<bool ATOMIC>
__global__ __launch_bounds__(256, 6) void kv_mfma_kernel(
    const float* __restrict__ K, const float* __restrict__ V,
    float* __restrict__ dst) {
    const int bh = blockIdx.y;
    const int blk = blockIdx.x;
    const int t = threadIdx.x;
    const int w = t >> 6, l = t & 63;

    __shared__ unsigned int KT[64 * 32];  // 8 KB: K'^T bf16 [d][s-pair] swizzled
    __shared__ unsigned int VT[64 * 32];  // 8 KB: V^T  bf16
    __shared__ float csumS[4][64];        // 1 KB: per-wave K' column sums

    const float* Kb = K + ((size_t)bh * SEQ + (size_t)blk * SCH) * DIM;
    const float* Vb = V + ((size_t)bh * SEQ + (size_t)blk * SCH) * DIM;

    const int c0 = (t & 15) * 4;  // staged col base (d rows c0..c0+3)
    const int lg = l >> 4;        // MFMA k-slice group 0..3
    const int lr = l & 15;        // MFMA row/col within tile

    f32x4 acc[4];
    #pragma unroll
    for (int m = 0; m < 4; ++m)
        #pragma unroll
        for (int r = 0; r < 4; ++r) acc[m][r] = 0.f;

    float cs0 = 0.f, cs1 = 0.f, cs2 = 0.f, cs3 = 0.f;

    #pragma unroll
    for (int st = 0; st < SUBT; ++st) {
        const float* Ks = Kb + (size_t)st * 64 * DIM;
        const float* Vs = Vb + (size_t)st * 64 * DIM;

        // stage 64 rows: each thread 2 (pair, col-chunk) slots
        #pragma unroll
        for (int i = 0; i < 2; ++i) {
            const int p = (t >> 4) + 16 * i;  // s-pair 0..31
            float4 ka = *(const float4*)(Ks + (size_t)(2 * p) * DIM + c0);
            float4 kb = *(const float4*)(Ks + (size_t)(2 * p + 1) * DIM + c0);
            const float4 va = *(const float4*)(Vs + (size_t)(2 * p) * DIM + c0);
            const float4 vb = *(const float4*)(Vs + (size_t)(2 * p + 1) * DIM + c0);
            elu4(ka); elu4(kb);
            cs0 += ka.x + kb.x; cs1 += ka.y + kb.y;
            cs2 += ka.z + kb.z; cs3 += ka.w + kb.w;
            KT[swz(c0 + 0, p)] = pack2bf(ka.x, kb.x);
            KT[swz(c0 + 1, p)] = pack2bf(ka.y, kb.y);
            KT[swz(c0 + 2, p)] = pack2bf(ka.z, kb.z);
            KT[swz(c0 + 3, p)] = pack2bf(ka.w, kb.w);
            VT[swz(c0 + 0, p)] = pack2bf(va.x, vb.x);
            VT[swz(c0 + 1, p)] = pack2bf(va.y, vb.y);
            VT[swz(c0 + 2, p)] = pack2bf(va.z, vb.z);
            VT[swz(c0 + 3, p)] = pack2bf(va.w, vb.w);
        }

        if (st == SUBT - 1) {
            // fold column sums across the wave's 16-lane groups (lanes l, l+16, l+32, l+48
            // share c0), then lanes 0..15 publish the wave partial.
            cs0 += __shfl_xor(cs0, 16); cs0 += __shfl_xor(cs0, 32);
            cs1 += __shfl_xor(cs1, 16); cs1 += __shfl_xor(cs1, 32);
            cs2 += __shfl_xor(cs2, 16); cs2 += __shfl_xor(cs2, 32);
            cs3 += __shfl_xor(cs3, 16); cs3 += __shfl_xor(cs3, 32);
            if (l < 16) *(float4*)&csumS[w][l * 4] = make_float4(cs0, cs1, cs2, cs3);
        }
        __syncthreads();

        // MFMA: wave w owns e-cols [16w,16w+16); K=64 (2 steps of 32)
        #pragma unroll
        for (int ks = 0; ks < 2; ++ks) {
            const int s2b = ks * 16 + lg * 4;  // 16B-aligned dword base
            const bf16x8 bfrag =
                *reinterpret_cast<const bf16x8*>(&VT[swz(16 * w + lr, s2b)]);
            #pragma unroll
            for (int m = 0; m < 4; ++m) {
                const bf16x8 afrag =
                    *reinterpret_cast<const bf16x8*>(&KT[swz(16 * m + lr, s2b)]);
                acc[m] = __builtin_amdgcn_mfma_f32_16x16x32_bf16(afrag, bfrag, acc[m],
                                                                 0, 0, 0);
            }
        }
        if (st < SUBT - 1) __syncthreads();  // protect overwrite of KT/VT
    }

    float* wout = ATOMIC ? dst + (size_t)bh * KVELEM
                         : dst + ((size_t)blk * BH + bh) * KVELEM;

    // ksum: fold the 4 wave partials (csumS visible since last pre-MFMA barrier)
    if (t < 64) {
        const float s = csumS[0][t] + csumS[1][t] + csumS[2][t] + csumS[3][t];
        if (ATOMIC) atomicAdd(&wout[DIM * DIM + t], s);
        else        wout[DIM * DIM + t] = s;
    }

    // store D: tile m -> rows d=16m+4lg+r, col e=16w+lr
    #pragma unroll
    for (int m = 0; m < 4; ++m) {
        #pragma unroll
        for (int r = 0; r < 4; ++r) {
            const int d = 16 * m + 4 * lg + r;
            const int e = 16 * w + lr;
            if (ATOMIC) atomicAdd(&wout[(size_t)d * DIM + e], acc[m][r]);
            else        wout[(size_t)d * DIM + e] = acc[m][r];
        }
    }
}

__global__ __launch_bounds__(256) void reduce_partials_kernel(
    const float* __restrict__ partial, float* __restrict__ fin) {
    const int bh = blockIdx.y;
    const int j = blockIdx.x * 256 + threadIdx.x;
    if (j >= KVELEM) return;
    float s = 0.f;
    #pragma unroll
    for (int c = 0; c < NPB; ++c)
        s += partial[((size_t)c * BH + bh) * KVELEM + j];
    fin[(size_t)bh * KVELEM + j] = s;
}

// Pass 2: block = 256 thr (4 waves), 128 q-rows/block (32/wave). Thread tile 4x8.
// (Measured ~HBM roofline together with reduce; unchanged.)
__global__ __launch_bounds__(256) void out_kernel(
    const float* __restrict__ Q, const float* __restrict__ ws,
    float* __restrict__ out) {
    const int bh = blockIdx.y;
    const int rb = blockIdx.x;  // 128-row block
    const int wave = threadIdx.x >> 6, lane = threadIdx.x & 63;
    const int t = threadIdx.x;
    const int tr = lane >> 3;   // 0..7 -> rows 4tr..4tr+3 (within wave's 32)
    const int tc = lane & 7;    // 0..7 -> cols 8tc..8tc+7

    const float* w = ws + (size_t)bh * KVELEM;
    const float* Qw = Q + ((size_t)bh * SEQ + (size_t)rb * 128 + (size_t)wave * 32) * DIM;
    float* Ow = out + ((size_t)bh * SEQ + (size_t)rb * 128 + (size_t)wave * 32) * DIM;

    __shared__ float kvS[DIM][DIM];    // 16 KB
    __shared__ float ksumS[DIM];
    __shared__ float qS[4][32][DIM];   // 32 KB, per-wave, XOR-swizzled col-chunks

    // cooperative kv load (whole block, 4096 floats)
    #pragma unroll
    for (int i = 0; i < 4; ++i) {
        const int idx = (i * 256 + t) * 4;
        *(float4*)&kvS[idx >> 6][idx & 63] = *(const float4*)(w + idx);
    }
    if (t < DIM) ksumS[t] = w[DIM * DIM + t];

    // per-wave q stage: 32 rows x 64 cols, elu'd; col-chunk cc stored at cc^((row>>2)&7)
    #pragma unroll
    for (int it = 0; it < 8; ++it) {
        const int row = it * 4 + (lane >> 4);   // 0..31
        const int cc = lane & 15;               // col chunk 0..15
        float4 qv = *(const float4*)(Qw + (size_t)row * DIM + cc * 4);
        elu4(qv);
        *(float4*)&qS[wave][row][((cc ^ ((row >> 2) & 7)) & 15) * 4] = qv;
    }
    __syncthreads();

    float acc[4][8] = {{0.f}};
    float accd[4] = {0.f, 0.f, 0.f, 0.f};

    #pragma unroll 2
    for (int dc = 0; dc < 16; ++dc) {  // d-chunks of 4
        float4 qv[4];
        #pragma unroll
        for (int i = 0; i < 4; ++i)
            qv[i] = *(const float4*)&qS[wave][tr * 4 + i][((dc ^ tr) & 15) * 4];
        const float4 ks = *(const float4*)&ksumS[dc * 4];
        #pragma unroll
        for (int dd = 0; dd < 4; ++dd) {
            const int d = dc * 4 + dd;
            const float4 ka = *(const float4*)&kvS[d][tc * 8];
            const float4 kb = *(const float4*)&kvS[d][tc * 8 + 4];
            const float ksd = (&ks.x)[dd];
            #pragma unroll
            for (int i = 0; i < 4; ++i) {
                const float qq = (&qv[i].x)[dd];
                accd[i] += qq * ksd;
                acc[i][0] += qq * ka.x; acc[i][1] += qq * ka.y;
                acc[i][2] += qq * ka.z; acc[i][3] += qq * ka.w;
                acc[i][4] += qq * kb.x; acc[i][5] += qq * kb.y;
                acc[i][6] += qq * kb.z; acc[i][7] += qq * kb.w;
            }
        }
    }

    #pragma unroll
    for (int i = 0; i < 4; ++i) {
        const float inv = 1.f / (accd[i] + EPS_LA);
        float4 o0, o1;
        o0.x = acc[i][0] * inv; o0.y = acc[i][1] * inv;
        o0.z = acc[i][2] * inv; o0.w = acc[i][3] * inv;
        o1.x = acc[i][4] * inv; o1.y = acc[i][5] * inv;
        o1.z = acc[i][6] * inv; o1.w = acc[i][7] * inv;
        float* orow = Ow + (size_t)(tr * 4 + i) * DIM + tc * 8;
        *(float4*)(orow) = o0;
        *(float4*)(orow + 4) = o1;
    }
}

extern "C" void kernel_launch(void* const* d_in, const int* in_sizes, int n_in,
                              void* d_out, int out_size, void* d_ws, size_t ws_size,
                              hipStream_t stream) {
    const float* q = (const float*)d_in[0];
    const float* k = (const float*)d_in[1];
    const float* v = (const float*)d_in[2];
    float* out = (float*)d_out;
    float* ws = (float*)d_ws;

    const size_t partial_elems = (size_t)NPB * BH * KVELEM;
    const size_t need = (partial_elems + (size_t)BH * KVELEM) * sizeof(float);

    dim3 blk(256);
    const float* fin_ptr;
    if (ws_size >= need) {
        float* partial = ws;
        float* fin = ws + partial_elems;
        hipLaunchKernelGGL((kv_mfma_kernel<false>), dim3(NPB, BH), blk, 0, stream,
                           k, v, partial);
        hipLaunchKernelGGL(reduce_partials_kernel, dim3((KVELEM + 255) / 256, BH),
                           blk, 0, stream, partial, fin);
        fin_ptr = fin;
    } else {
        float* fin = ws;
        hipMemsetAsync(fin, 0, (size_t)BH * KVELEM * sizeof(float), stream);
        hipLaunchKernelGGL((kv_mfma_kernel<true>), dim3(NPB, BH), blk, 0, stream,
                           k, v, fin);
        fin_ptr = fin;
    }
    hipLaunchKernelGGL(out_kernel, dim3(SEQ / 128, BH), blk, 0, stream,
                       q, fin_ptr, out);
}

// Round 7
// 73.676 us; speedup vs baseline: 1.1136x; 1.1136x over previous
//
#include <hip/hip_runtime.h>

// LinearAttention fp32 [4,16,4096,64]: out = (Q' (K'^T V)) / (Q'.k_sum + eps), X' = elu(X)+1.
// Pass 1 (kv_mfma): 1024 blocks (4/CU, all resident), 256 s-rows each, processed as
//   4x 64-row tiles through a software pipeline: register-prefetch next tile's
//   global loads, elu/pack current tile -> double-buffered LDS (conflict-free
//   XOR swizzle), ONE barrier per tile, mfma_f32_16x16x32_bf16 accumulate.
//   ksum fp32 carried in registers, shfl-reduced at the end.
// Pass 1b (reduce_partials): fold NPB partials per bh.
// Pass 2 (out_kernel): unchanged (~HBM roofline).

#define EPS_LA 1e-6f

constexpr int BH = 64;
constexpr int SEQ = 4096;
constexpr int DIM = 64;
constexpr int KVELEM = DIM * DIM + DIM;  // 4160
constexpr int NPB = 16;                  // partial blocks per bh
constexpr int SCH = SEQ / NPB;           // 256 s-rows per block
constexpr int NT = SCH / 64;             // 4 tiles per block

typedef short bf16x8 __attribute__((ext_vector_type(8)));
typedef float f32x4 __attribute__((ext_vector_type(4)));

__device__ __forceinline__ float elu1(float x) {
    return x > 0.f ? x + 1.f : __expf(x);
}
__device__ __forceinline__ void elu4(float4& v) {
    v.x = elu1(v.x); v.y = elu1(v.y); v.z = elu1(v.z); v.w = elu1(v.w);
}

// fp32 -> bf16 (RNE; inputs finite)
__device__ __forceinline__ unsigned int f2bf(float x) {
    unsigned int u = __float_as_uint(x);
    return (u + 0x7fffu + ((u >> 16) & 1u)) >> 16;
}
__device__ __forceinline__ unsigned int pack2bf(float lo, float hi) {
    return f2bf(lo) | (f2bf(hi) << 16);
}

// Dword index into KT/VT[64 d-rows][32 s-pairs]; staging b32 writes 2 lanes/bank
// (free), MFMA b128 reads at the b128 minimum. Keeps 16B alignment.
__device__ __forceinline__ int swz(int d, int s2) {
    return d * 32 + (s2 ^ ((((d >> 1) ^ (d >> 2)) & 7) << 2));
}

template<bool ATOMIC>
__global__ __launch_bounds__(256, 4) void kv_mfma_kernel(
    const float* __restrict__ K, const float* __restrict__ V,
    float* __restrict__ dst) {
    const int bh = blockIdx.y;
    const int blk = blockIdx.x;
    const int t = threadIdx.x;
    const int w = t >> 6, l = t & 63;

    __shared__ unsigned int KT[2][64 * 32];  // 2 x 8 KB, double-buffered
    __shared__ unsigned int VT[2][64 * 32];  // 2 x 8 KB
    __shared__ float csumS[4][64];           // 1 KB

    const float* Kb = K + ((size_t)bh * SEQ + (size_t)blk * SCH) * DIM;
    const float* Vb = V + ((size_t)bh * SEQ + (size_t)blk * SCH) * DIM;

    const int c0 = (t & 15) * 4;  // staged col base (d rows c0..c0+3)
    const int pr = t >> 4;        // s-pair base 0..15 (pairs pr, pr+16)
    const int lg = l >> 4;        // MFMA k-slice group 0..3
    const int lr = l & 15;        // MFMA row/col within tile

    f32x4 acc[4];
    #pragma unroll
    for (int m = 0; m < 4; ++m)
        #pragma unroll
        for (int r = 0; r < 4; ++r) acc[m][r] = 0.f;

    float cs0 = 0.f, cs1 = 0.f, cs2 = 0.f, cs3 = 0.f;

    // two register sets (indices become literals after full unroll)
    float4 ka[2][2], kb[2][2], va[2][2], vb[2][2];

    // prologue: tile 0 -> set 0
    #pragma unroll
    for (int i = 0; i < 2; ++i) {
        const int p = pr + 16 * i;
        const float* Ks = Kb + (size_t)(2 * p) * DIM + c0;
        const float* Vs = Vb + (size_t)(2 * p) * DIM + c0;
        ka[0][i] = *(const float4*)Ks;
        kb[0][i] = *(const float4*)(Ks + DIM);
        va[0][i] = *(const float4*)Vs;
        vb[0][i] = *(const float4*)(Vs + DIM);
    }

    #pragma unroll
    for (int st = 0; st < NT; ++st) {
        const int cur = st & 1;
        const int nxt = cur ^ 1;

        // issue next tile's loads first (independent; stay outstanding under pack+MFMA)
        if (st + 1 < NT) {
            #pragma unroll
            for (int i = 0; i < 2; ++i) {
                const int p = pr + 16 * i;
                const float* Ks = Kb + ((size_t)(st + 1) * 64 + 2 * p) * DIM + c0;
                const float* Vs = Vb + ((size_t)(st + 1) * 64 + 2 * p) * DIM + c0;
                ka[nxt][i] = *(const float4*)Ks;
                kb[nxt][i] = *(const float4*)(Ks + DIM);
                va[nxt][i] = *(const float4*)Vs;
                vb[nxt][i] = *(const float4*)(Vs + DIM);
            }
        }

        // elu + pack current set into LDS buffer `cur`
        #pragma unroll
        for (int i = 0; i < 2; ++i) {
            const int p = pr + 16 * i;
            float4 kka = ka[cur][i], kkb = kb[cur][i];
            elu4(kka); elu4(kkb);
            cs0 += kka.x + kkb.x; cs1 += kka.y + kkb.y;
            cs2 += kka.z + kkb.z; cs3 += kka.w + kkb.w;
            KT[cur][swz(c0 + 0, p)] = pack2bf(kka.x, kkb.x);
            KT[cur][swz(c0 + 1, p)] = pack2bf(kka.y, kkb.y);
            KT[cur][swz(c0 + 2, p)] = pack2bf(kka.z, kkb.z);
            KT[cur][swz(c0 + 3, p)] = pack2bf(kka.w, kkb.w);
            const float4 vva = va[cur][i], vvb = vb[cur][i];
            VT[cur][swz(c0 + 0, p)] = pack2bf(vva.x, vvb.x);
            VT[cur][swz(c0 + 1, p)] = pack2bf(vva.y, vvb.y);
            VT[cur][swz(c0 + 2, p)] = pack2bf(vva.z, vvb.z);
            VT[cur][swz(c0 + 3, p)] = pack2bf(vva.w, vvb.w);
        }

        if (st == NT - 1) {
            // fold column sums across 16-lane groups; lanes 0..15 publish wave partial
            cs0 += __shfl_xor(cs0, 16); cs0 += __shfl_xor(cs0, 32);
            cs1 += __shfl_xor(cs1, 16); cs1 += __shfl_xor(cs1, 32);
            cs2 += __shfl_xor(cs2, 16); cs2 += __shfl_xor(cs2, 32);
            cs3 += __shfl_xor(cs3, 16); cs3 += __shfl_xor(cs3, 32);
            if (l < 16) *(float4*)&csumS[w][l * 4] = make_float4(cs0, cs1, cs2, cs3);
        }

        __syncthreads();  // single barrier per tile (dbuf makes WAR safe)

        // MFMA: wave w owns e-cols [16w,16w+16); K=64 (2 steps of 32)
        #pragma unroll
        for (int ks2 = 0; ks2 < 2; ++ks2) {
            const int s2b = ks2 * 16 + lg * 4;  // 16B-aligned dword base
            const bf16x8 bfrag =
                *reinterpret_cast<const bf16x8*>(&VT[cur][swz(16 * w + lr, s2b)]);
            #pragma unroll
            for (int m = 0; m < 4; ++m) {
                const bf16x8 afrag =
                    *reinterpret_cast<const bf16x8*>(&KT[cur][swz(16 * m + lr, s2b)]);
                acc[m] = __builtin_amdgcn_mfma_f32_16x16x32_bf16(afrag, bfrag, acc[m],
                                                                 0, 0, 0);
            }
        }
    }

    float* wout = ATOMIC ? dst + (size_t)bh * KVELEM
                         : dst + ((size_t)blk * BH + bh) * KVELEM;

    // ksum: fold the 4 wave partials (visible since the last barrier)
    if (t < 64) {
        const float s = csumS[0][t] + csumS[1][t] + csumS[2][t] + csumS[3][t];
        if (ATOMIC) atomicAdd(&wout[DIM * DIM + t], s);
        else        wout[DIM * DIM + t] = s;
    }

    // store D: tile m -> rows d=16m+4lg+r, col e=16w+lr
    #pragma unroll
    for (int m = 0; m < 4; ++m) {
        #pragma unroll
        for (int r = 0; r < 4; ++r) {
            const int d = 16 * m + 4 * lg + r;
            const int e = 16 * w + lr;
            if (ATOMIC) atomicAdd(&wout[(size_t)d * DIM + e], acc[m][r]);
            else        wout[(size_t)d * DIM + e] = acc[m][r];
        }
    }
}

__global__ __launch_bounds__(256) void reduce_partials_kernel(
    const float* __restrict__ partial, float* __restrict__ fin) {
    const int bh = blockIdx.y;
    const int j = blockIdx.x * 256 + threadIdx.x;
    if (j >= KVELEM) return;
    float s = 0.f;
    #pragma unroll
    for (int c = 0; c < NPB; ++c)
        s += partial[((size_t)c * BH + bh) * KVELEM + j];
    fin[(size_t)bh * KVELEM + j] = s;
}

// Pass 2: block = 256 thr (4 waves), 128 q-rows/block (32/wave). Thread tile 4x8.
// (Measured ~HBM roofline; unchanged.)
__global__ __launch_bounds__(256) void out_kernel(
    const float* __restrict__ Q, const float* __restrict__ ws,
    float* __restrict__ out) {
    const int bh = blockIdx.y;
    const int rb = blockIdx.x;  // 128-row block
    const int wave = threadIdx.x >> 6, lane = threadIdx.x & 63;
    const int t = threadIdx.x;
    const int tr = lane >> 3;   // 0..7 -> rows 4tr..4tr+3 (within wave's 32)
    const int tc = lane & 7;    // 0..7 -> cols 8tc..8tc+7

    const float* w = ws + (size_t)bh * KVELEM;
    const float* Qw = Q + ((size_t)bh * SEQ + (size_t)rb * 128 + (size_t)wave * 32) * DIM;
    float* Ow = out + ((size_t)bh * SEQ + (size_t)rb * 128 + (size_t)wave * 32) * DIM;

    __shared__ float kvS[DIM][DIM];    // 16 KB
    __shared__ float ksumS[DIM];
    __shared__ float qS[4][32][DIM];   // 32 KB, per-wave, XOR-swizzled col-chunks

    // cooperative kv load (whole block, 4096 floats)
    #pragma unroll
    for (int i = 0; i < 4; ++i) {
        const int idx = (i * 256 + t) * 4;
        *(float4*)&kvS[idx >> 6][idx & 63] = *(const float4*)(w + idx);
    }
    if (t < DIM) ksumS[t] = w[DIM * DIM + t];

    // per-wave q stage: 32 rows x 64 cols, elu'd; col-chunk cc stored at cc^((row>>2)&7)
    #pragma unroll
    for (int it = 0; it < 8; ++it) {
        const int row = it * 4 + (lane >> 4);   // 0..31
        const int cc = lane & 15;               // col chunk 0..15
        float4 qv = *(const float4*)(Qw + (size_t)row * DIM + cc * 4);
        elu4(qv);
        *(float4*)&qS[wave][row][((cc ^ ((row >> 2) & 7)) & 15) * 4] = qv;
    }
    __syncthreads();

    float acc[4][8] = {{0.f}};
    float accd[4] = {0.f, 0.f, 0.f, 0.f};

    #pragma unroll 2
    for (int dc = 0; dc < 16; ++dc) {  // d-chunks of 4
        float4 qv[4];
        #pragma unroll
        for (int i = 0; i < 4; ++i)
            qv[i] = *(const float4*)&qS[wave][tr * 4 + i][((dc ^ tr) & 15) * 4];
        const float4 ks = *(const float4*)&ksumS[dc * 4];
        #pragma unroll
        for (int dd = 0; dd < 4; ++dd) {
            const int d = dc * 4 + dd;
            const float4 ka = *(const float4*)&kvS[d][tc * 8];
            const float4 kb = *(const float4*)&kvS[d][tc * 8 + 4];
            const float ksd = (&ks.x)[dd];
            #pragma unroll
            for (int i = 0; i < 4; ++i) {
                const float qq = (&qv[i].x)[dd];
                accd[i] += qq * ksd;
                acc[i][0] += qq * ka.x; acc[i][1] += qq * ka.y;
                acc[i][2] += qq * ka.z; acc[i][3] += qq * ka.w;
                acc[i][4] += qq * kb.x; acc[i][5] += qq * kb.y;
                acc[i][6] += qq * kb.z; acc[i][7] += qq * kb.w;
            }
        }
    }

    #pragma unroll
    for (int i = 0; i < 4; ++i) {
        const float inv = 1.f / (accd[i] + EPS_LA);
        float4 o0, o1;
        o0.x = acc[i][0] * inv; o0.y = acc[i][1] * inv;
        o0.z = acc[i][2] * inv; o0.w = acc[i][3] * inv;
        o1.x = acc[i][4] * inv; o1.y = acc[i][5] * inv;
        o1.z = acc[i][6] * inv; o1.w = acc[i][7] * inv;
        float* orow = Ow + (size_t)(tr * 4 + i) * DIM + tc * 8;
        *(float4*)(orow) = o0;
        *(float4*)(orow + 4) = o1;
    }
}

extern "C" void kernel_launch(void* const* d_in, const int* in_sizes, int n_in,
                              void* d_out, int out_size, void* d_ws, size_t ws_size,
                              hipStream_t stream) {
    const float* q = (const float*)d_in[0];
    const float* k = (const float*)d_in[1];
    const float* v = (const float*)d_in[2];
    float* out = (float*)d_out;
    float* ws = (float*)d_ws;

    const size_t partial_elems = (size_t)NPB * BH * KVELEM;
    const size_t need = (partial_elems + (size_t)BH * KVELEM) * sizeof(float);

    dim3 blk(256);
    const float* fin_ptr;
    if (ws_size >= need) {
        float* partial = ws;
        float* fin = ws + partial_elems;
        hipLaunchKernelGGL((kv_mfma_kernel<false>), dim3(NPB, BH), blk, 0, stream,
                           k, v, partial);
        hipLaunchKernelGGL(reduce_partials_kernel, dim3((KVELEM + 255) / 256, BH),
                           blk, 0, stream, partial, fin);
        fin_ptr = fin;
    } else {
        float* fin = ws;
        hipMemsetAsync(fin, 0, (size_t)BH * KVELEM * sizeof(float), stream);
        hipLaunchKernelGGL((kv_mfma_kernel<true>), dim3(NPB, BH), blk, 0, stream,
                           k, v, fin);
        fin_ptr = fin;
    }
    hipLaunchKernelGGL(out_kernel, dim3(SEQ / 128, BH), blk, 0, stream,
                       q, fin_ptr, out);
}